// Round 1
// baseline (49685.754 us; speedup 1.0000x reference)
//
#include <hip/hip_runtime.h>
#include <math.h>

#define BB 64
#define LQ 1024
#define KVD 256
#define HD 512
#define ED 256
#define TT 300
#define VV 33
#define MHD 512
#define G4 2048

// ws float offsets
#define OFF_WPK     0L            // 6 * 1048576 (Wih0,Whh0,Wih1,Whh1,Wih2,Whh2) packed [k4][2048 r][4]
#define OFF_BIAS    6291456L      // 3*2048 combined bih+bhh in cell order r=m*4+g
#define OFF_WFC     6297600L      // [128][256][4]
#define OFF_WM1     6428672L      // [128][512][4]
#define OFF_WM2T    6690816L      // [512][33]
#define OFF_WEMBT   6707712L      // [33][256]
#define OFF_H       6716160L      // [2 slot][3 layer][64][512]
#define OFF_C       6912768L
#define OFF_RNN     7109376L      // [2][64][512]
#define OFF_P1      7174912L      // [64][2048]
#define OFF_P2      7305984L
#define OFF_QUERY   7437056L      // [64][256]
#define OFF_ENERGY  7453440L      // [64][1024]
#define OFF_STATS   7518976L      // [64][4][2]
#define OFF_CTXP    7519488L      // [64][4][256]
#define OFF_ATT     7585024L      // [300][65536]
#define WS_FLOATS_FULL  27245824L

// out float offsets
#define OUT_Y      0L
#define OUT_LBL    633600L
#define OUT_LPT    652800L
#define OUT_ATT    672000L

// ---------------- packing ----------------
__global__ __launch_bounds__(256) void k_pack_gates(
    const float* __restrict__ Wih0, const float* __restrict__ Whh0,
    const float* __restrict__ Wih1, const float* __restrict__ Whh1,
    const float* __restrict__ Wih2, const float* __restrict__ Whh2,
    const float* __restrict__ bih0, const float* __restrict__ bhh0,
    const float* __restrict__ bih1, const float* __restrict__ bhh1,
    const float* __restrict__ bih2, const float* __restrict__ bhh2,
    float* __restrict__ ws)
{
    long id = (long)blockIdx.x * 256 + threadIdx.x;
    if (id < 6L * 262144L) {
        int mat = (int)(id / 262144L);
        int rem = (int)(id % 262144L);
        int k4 = rem >> 11;
        int r  = rem & 2047;
        int m = r >> 2, g = r & 3;
        int row = g * HD + m;
        const float* W = (mat==0)?Wih0:(mat==1)?Whh0:(mat==2)?Wih1:(mat==3)?Whh1:(mat==4)?Wih2:Whh2;
        const float4 v = *reinterpret_cast<const float4*>(W + (long)row * HD + k4 * 4);
        *reinterpret_cast<float4*>(ws + OFF_WPK + ((long)mat * 262144L + rem) * 4) = v;
    } else {
        long bid = id - 6L * 262144L;
        if (bid < 3L * 2048L) {
            int l = (int)(bid / 2048), r = (int)(bid % 2048);
            int m = r >> 2, g = r & 3;
            int row = g * HD + m;
            const float* bi = (l==0)?bih0:(l==1)?bih1:bih2;
            const float* bh = (l==0)?bhh0:(l==1)?bhh1:bhh2;
            ws[OFF_BIAS + bid] = bi[row] + bh[row];
        }
    }
}

__global__ __launch_bounds__(256) void k_pack_small(
    const float* __restrict__ W_fc, const float* __restrict__ W_mlp1,
    const float* __restrict__ W_mlp2, const float* __restrict__ W_emb,
    float* __restrict__ ws)
{
    int id = blockIdx.x * 256 + threadIdx.x;
    if (id < 32768) {           // Wfc pack: (k4, kv)
        int k4 = id >> 8, kv = id & 255;
        const float4 v = *reinterpret_cast<const float4*>(W_fc + (long)kv * HD + k4 * 4);
        *reinterpret_cast<float4*>(ws + OFF_WFC + (long)id * 4) = v;
        return;
    }
    id -= 32768;
    if (id < 65536) {           // Wm1 pack: (k4, m)
        int k4 = id >> 9, m = id & 511;
        const float4 v = *reinterpret_cast<const float4*>(W_mlp1 + (long)m * HD + k4 * 4);
        *reinterpret_cast<float4*>(ws + OFF_WM1 + (long)id * 4) = v;
        return;
    }
    id -= 65536;
    if (id < 512 * VV) {        // Wm2T[m][v]
        int m = id / VV, v = id % VV;
        ws[OFF_WM2T + id] = W_mlp2[(long)v * MHD + m];
        return;
    }
    id -= 512 * VV;
    if (id < VV * 256) {        // WembT[v][e]
        int v = id >> 8, e = id & 255;
        ws[OFF_WEMBT + id] = W_emb[(long)e * VV + v];
    }
}

__global__ __launch_bounds__(256) void k_init(
    const float* __restrict__ W_emb, const float* __restrict__ b_emb, float* __restrict__ ws)
{
    int id = blockIdx.x * 256 + threadIdx.x;
    if (id < 98304) { ws[OFF_H + id] = 0.f; ws[OFF_C + id] = 0.f; return; }
    id -= 98304;
    if (id < BB * HD) {
        int k = id & 511;
        float v = 0.f;
        if (k < ED) v = W_emb[(long)k * VV + 0] + b_emb[k];
        ws[OFF_RNN + id] = v;
    }
}

// ---------------- gates core (32 b x 16 r per block) ----------------
__device__ __forceinline__ void gates_mac(
    float acc[2], const float* __restrict__ inp, const float* __restrict__ Wpk,
    int r0, int jl, int bg, float (*ldsIn)[132], int tid)
{
    for (int kc = 0; kc < 4; ++kc) {
        __syncthreads();
        {
            int fid = tid;
            #pragma unroll
            for (int i = 0; i < 4; ++i, fid += 256) {
                int brow = fid >> 5, k4 = fid & 31;
                float4 v = *reinterpret_cast<const float4*>(inp + (long)brow * HD + kc * 128 + k4 * 4);
                *reinterpret_cast<float4*>(&ldsIn[brow][k4 * 4]) = v;
            }
        }
        __syncthreads();
        const float* Wb = Wpk + ((long)(kc * 32) * G4 + (r0 + jl)) * 4;
        #pragma unroll 4
        for (int k4 = 0; k4 < 32; ++k4) {
            float4 w = *reinterpret_cast<const float4*>(Wb + (long)k4 * G4 * 4);
            float4 x0 = *reinterpret_cast<const float4*>(&ldsIn[bg][k4 * 4]);
            float4 x1 = *reinterpret_cast<const float4*>(&ldsIn[bg + 16][k4 * 4]);
            acc[0] += x0.x * w.x + x0.y * w.y + x0.z * w.z + x0.w * w.w;
            acc[1] += x1.x * w.x + x1.y * w.y + x1.z * w.z + x1.w * w.w;
        }
    }
}

__device__ __forceinline__ void cell_store(
    float acc[2], int r0, int bhalf, int tid,
    const float* __restrict__ cOld, float* __restrict__ cNew, float* __restrict__ hNew,
    float (*g)[33])
{
    int jl = tid & 15, bg = tid >> 4;
    g[jl][bg] = acc[0];
    g[jl][bg + 16] = acc[1];
    __syncthreads();
    if (tid < 128) {
        int hc = tid >> 5, bl = tid & 31;
        int b = bhalf * 32 + bl;
        int m = (r0 >> 2) + hc;
        float gi = g[hc * 4 + 0][bl];
        float gf = g[hc * 4 + 1][bl];
        float gG = g[hc * 4 + 2][bl];
        float go = g[hc * 4 + 3][bl];
        float si = 1.f / (1.f + expf(-gi));
        float sf = 1.f / (1.f + expf(-gf));
        float tg = tanhf(gG);
        float so = 1.f / (1.f + expf(-go));
        float c2 = sf * cOld[(long)b * HD + m] + si * tg;
        cNew[(long)b * HD + m] = c2;
        hNew[(long)b * HD + m] = so * tanhf(c2);
    }
}

// phase A: full gates layer0 (+cell) and Whh partials for layers 1,2
__global__ __launch_bounds__(256) void k_pa(float* __restrict__ ws, int t)
{
    __shared__ float ldsIn[32][132];
    __shared__ float gx[16][33];
    int so = t & 1, sn = 1 - so;
    int bx = blockIdx.x, tid = threadIdx.x;
    int jl = tid & 15, bg = tid >> 4;
    float* h = ws + OFF_H;
    float* c = ws + OFF_C;
    const float* Wpk = ws + OFF_WPK;
    if (bx < 256) {
        int px = bx >> 1, bh = bx & 1;
        int r0 = px * 16;
        float bias = ws[OFF_BIAS + r0 + jl];
        float acc[2] = {bias, bias};
        const float* rnn = ws + OFF_RNN + (long)so * 32768 + (long)bh * 32 * HD;
        const float* h0o = h + ((long)so * 3 + 0) * 32768 + (long)bh * 32 * HD;
        gates_mac(acc, rnn, Wpk + 0L * 1048576L, r0, jl, bg, ldsIn, tid);
        gates_mac(acc, h0o, Wpk + 1L * 1048576L, r0, jl, bg, ldsIn, tid);
        __syncthreads();
        cell_store(acc, r0, bh, tid,
                   c + ((long)so * 3 + 0) * 32768,
                   c + ((long)sn * 3 + 0) * 32768,
                   h + ((long)sn * 3 + 0) * 32768, gx);
    } else if (bx < 512) {
        int px = (bx - 256) >> 1, bh = bx & 1;
        int r0 = px * 16;
        float bias = ws[OFF_BIAS + 2048 + r0 + jl];
        float acc[2] = {bias, bias};
        const float* h1o = h + ((long)so * 3 + 1) * 32768 + (long)bh * 32 * HD;
        gates_mac(acc, h1o, Wpk + 3L * 1048576L, r0, jl, bg, ldsIn, tid);
        float* P = ws + OFF_P1 + (long)bh * 32 * G4;
        P[(long)bg * G4 + r0 + jl] = acc[0];
        P[(long)(bg + 16) * G4 + r0 + jl] = acc[1];
    } else {
        int px = (bx - 512) >> 1, bh = bx & 1;
        int r0 = px * 16;
        float bias = ws[OFF_BIAS + 4096 + r0 + jl];
        float acc[2] = {bias, bias};
        const float* h2o = h + ((long)so * 3 + 2) * 32768 + (long)bh * 32 * HD;
        gates_mac(acc, h2o, Wpk + 5L * 1048576L, r0, jl, bg, ldsIn, tid);
        float* P = ws + OFF_P2 + (long)bh * 32 * G4;
        P[(long)bg * G4 + r0 + jl] = acc[0];
        P[(long)(bg + 16) * G4 + r0 + jl] = acc[1];
    }
}

// phase B/C: gates layer 'layer' = P + h(layer-1,new)@Wih^T, + cell
__global__ __launch_bounds__(256) void k_pbc(float* __restrict__ ws, int t, int layer)
{
    __shared__ float ldsIn[32][132];
    __shared__ float gx[16][33];
    int so = t & 1, sn = 1 - so;
    int bx = blockIdx.x, tid = threadIdx.x;
    int jl = tid & 15, bg = tid >> 4;
    int px = bx >> 1, bh = bx & 1, r0 = px * 16;
    float* h = ws + OFF_H;
    float* c = ws + OFF_C;
    const float* P = ws + ((layer == 1) ? OFF_P1 : OFF_P2) + (long)bh * 32 * G4;
    float acc[2] = { P[(long)bg * G4 + r0 + jl], P[(long)(bg + 16) * G4 + r0 + jl] };
    const float* hin = h + ((long)sn * 3 + (layer - 1)) * 32768 + (long)bh * 32 * HD;
    long mat = (layer == 1) ? 2L : 4L;
    gates_mac(acc, hin, ws + OFF_WPK + mat * 1048576L, r0, jl, bg, ldsIn, tid);
    __syncthreads();
    cell_store(acc, r0, bh, tid,
               c + ((long)so * 3 + layer) * 32768,
               c + ((long)sn * 3 + layer) * 32768,
               h + ((long)sn * 3 + layer) * 32768, gx);
}

__global__ __launch_bounds__(256) void k_query(
    const float* __restrict__ b_fc, float* __restrict__ ws, int t)
{
    __shared__ float h2l[512];
    int b = blockIdx.x, tid = threadIdx.x;
    int sn = 1 - (t & 1);
    const float* h2 = ws + OFF_H + ((long)sn * 3 + 2) * 32768 + (long)b * HD;
    h2l[tid] = h2[tid];
    h2l[tid + 256] = h2[tid + 256];
    __syncthreads();
    float acc = b_fc[tid];
    const float* Wf = ws + OFF_WFC;
    #pragma unroll 4
    for (int k4 = 0; k4 < 128; ++k4) {
        float4 w = *reinterpret_cast<const float4*>(Wf + ((long)k4 * 256 + tid) * 4);
        float4 x = *reinterpret_cast<const float4*>(&h2l[k4 * 4]);
        acc += x.x * w.x + x.y * w.y + x.z * w.z + x.w * w.w;
    }
    ws[OFF_QUERY + (long)b * 256 + tid] = acc;
}

__global__ __launch_bounds__(256) void k_energy(
    const float* __restrict__ enc_key, const int* __restrict__ fsl, float* __restrict__ ws)
{
    __shared__ float eL[256];
    __shared__ float wred[4];
    __shared__ float sred[4];
    int bx = blockIdx.x;
    int b = bx >> 2, ch = bx & 3;
    int tid = threadIdx.x, w = tid >> 6, lane = tid & 63;
    float4 q4 = *reinterpret_cast<const float4*>(ws + OFF_QUERY + (long)b * 256 + lane * 4);
    int n = fsl[b];
    float wmax = -3.4e38f;
    for (int i = 0; i < 64; ++i) {
        int lloc = w * 64 + i;
        int l = ch * 256 + lloc;
        const float4 k4 = *reinterpret_cast<const float4*>(
            enc_key + ((long)(b * LQ + l)) * KVD + lane * 4);
        float s = k4.x * q4.x + k4.y * q4.y + k4.z * q4.z + k4.w * q4.w;
        #pragma unroll
        for (int off = 32; off; off >>= 1) s += __shfl_xor(s, off, 64);
        float e = (l < n) ? s : 0.f;   // softmax(energy * mask): masked -> 0, still in softmax
        if (lane == 0) { eL[lloc] = e; ws[OFF_ENERGY + (long)b * LQ + l] = e; }
        wmax = fmaxf(wmax, e);
    }
    if (lane == 0) wred[w] = wmax;
    __syncthreads();
    float mc = fmaxf(fmaxf(wred[0], wred[1]), fmaxf(wred[2], wred[3]));
    float p = expf(eL[tid] - mc);
    #pragma unroll
    for (int off = 32; off; off >>= 1) p += __shfl_xor(p, off, 64);
    if (lane == 0) sred[w] = p;
    __syncthreads();
    if (tid == 0) {
        ws[OFF_STATS + ((long)b * 4 + ch) * 2 + 0] = mc;
        ws[OFF_STATS + ((long)b * 4 + ch) * 2 + 1] = sred[0] + sred[1] + sred[2] + sred[3];
    }
}

__global__ __launch_bounds__(256) void k_ctx(
    const float* __restrict__ enc_value, float* __restrict__ ws,
    float* __restrict__ attdst, int attDirect, int t)
{
    __shared__ float al[256];
    int bx = blockIdx.x;
    int b = bx >> 2, ch = bx & 3;
    int tid = threadIdx.x;
    const float* st = ws + OFF_STATS + (long)b * 8;
    float m0 = st[0], s0 = st[1], m1 = st[2], s1 = st[3];
    float m2 = st[4], s2 = st[5], m3 = st[6], s3 = st[7];
    float m = fmaxf(fmaxf(m0, m1), fmaxf(m2, m3));
    float S = s0 * expf(m0 - m) + s1 * expf(m1 - m) + s2 * expf(m2 - m) + s3 * expf(m3 - m);
    float e = ws[OFF_ENERGY + (long)b * LQ + ch * 256 + tid];
    float a = expf(e - m) / S;
    al[tid] = a;
    if (attDirect) attdst[((long)(b * LQ + ch * 256 + tid)) * TT + t] = a;
    else           attdst[(long)t * 65536 + b * LQ + ch * 256 + tid] = a;
    __syncthreads();
    float acc = 0.f;
    const float* vbase = enc_value + ((long)(b * LQ + ch * 256)) * KVD + tid;
    #pragma unroll 8
    for (int i = 0; i < 256; ++i) acc += al[i] * vbase[(long)i * KVD];
    ws[OFF_CTXP + ((long)b * 4 + ch) * 256 + tid] = acc;
}

__global__ __launch_bounds__(256) void k_final(
    const float* __restrict__ gumbel_u, const float* __restrict__ b_mlp1,
    const float* __restrict__ b_mlp2, const float* __restrict__ b_emb,
    float* __restrict__ ws, float* __restrict__ out, int t)
{
    __shared__ float cat[512];
    __shared__ float hm[512];
    __shared__ float yp[4][33];
    __shared__ float sv[33];
    __shared__ float ysm[33];
    int b = blockIdx.x, tid = threadIdx.x;
    int sn = 1 - (t & 1);
    const float* cp = ws + OFF_CTXP + (long)b * 1024;
    float ctx = cp[tid] + cp[256 + tid] + cp[512 + tid] + cp[768 + tid];
    cat[256 + tid] = ctx;
    cat[tid] = ws[OFF_QUERY + (long)b * 256 + tid];
    ws[OFF_RNN + (long)sn * 32768 + (long)b * HD + 256 + tid] = ctx;
    __syncthreads();
    float a0 = b_mlp1[tid], a1 = b_mlp1[tid + 256];
    const float* Wm1 = ws + OFF_WM1;
    #pragma unroll 2
    for (int k4 = 0; k4 < 128; ++k4) {
        float4 x  = *reinterpret_cast<const float4*>(&cat[k4 * 4]);
        float4 wA = *reinterpret_cast<const float4*>(Wm1 + ((long)k4 * 512 + tid) * 4);
        float4 wB = *reinterpret_cast<const float4*>(Wm1 + ((long)k4 * 512 + tid + 256) * 4);
        a0 += x.x * wA.x + x.y * wA.y + x.z * wA.z + x.w * wA.w;
        a1 += x.x * wB.x + x.y * wB.y + x.z * wB.z + x.w * wB.w;
    }
    hm[tid]       = (a0 >= 0.f) ? a0 : 0.9f * a0;   // LeakyReLU(0.9)
    hm[tid + 256] = (a1 >= 0.f) ? a1 : 0.9f * a1;
    __syncthreads();
    int w = tid >> 6, lane = tid & 63;
    if (lane < VV) {
        float acc = 0.f;
        const float* W2 = ws + OFF_WM2T;
        for (int m = w * 128; m < w * 128 + 128; ++m) acc += hm[m] * W2[(long)m * VV + lane];
        yp[w][lane] = acc;
    }
    __syncthreads();
    if (tid < VV) {
        float y = yp[0][tid] + yp[1][tid] + yp[2][tid] + yp[3][tid] + b_mlp2[tid];
        out[OUT_Y + ((long)b * TT + t) * VV + tid] = y;
        float u = gumbel_u[((long)t * BB + b) * VV + tid];
        float g = -logf(-logf(u + 1e-10f) + 1e-10f);
        sv[tid] = y + g;
    }
    __syncthreads();
    if (tid == 0) {
        float mx = sv[0]; int am = 0;
        for (int v = 1; v < VV; ++v) if (sv[v] > mx) { mx = sv[v]; am = v; }  // first-max
        float Z = 0.f;
        for (int v = 0; v < VV; ++v) { float p = expf(sv[v] - mx); ysm[v] = p; Z += p; }
        float iz = 1.f / Z;
        for (int v = 0; v < VV; ++v) ysm[v] *= iz;
        out[OUT_LBL + (long)b * TT + t] = (float)am;
    }
    __syncthreads();
    float acc = b_emb[tid];
    const float* We = ws + OFF_WEMBT;
    #pragma unroll
    for (int v = 0; v < VV; ++v) acc += ysm[v] * We[(long)v * 256 + tid];
    ws[OFF_RNN + (long)sn * 32768 + (long)b * HD + tid] = acc;
}

__global__ __launch_bounds__(256) void k_labels(const int* __restrict__ lp, float* __restrict__ out)
{
    int id = blockIdx.x * 256 + threadIdx.x;
    if (id < BB * TT) {
        int b = id / TT, t = id % TT;
        out[OUT_LPT + id] = (float)lp[(long)t * BB + b];
    }
}

__global__ __launch_bounds__(256) void k_att_tr(const float* __restrict__ src, float* __restrict__ out)
{
    __shared__ float tile[32][33];
    int blt = blockIdx.x;
    int ttb = blockIdx.y;
    int tx = threadIdx.x & 31, ty = threadIdx.x >> 5;
    int bl0 = blt * 32, t0 = ttb * 32;
    #pragma unroll
    for (int j = 0; j < 4; ++j) {
        int trow = t0 + ty + j * 8;
        if (trow < TT) tile[ty + j * 8][tx] = src[(long)trow * 65536 + bl0 + tx];
    }
    __syncthreads();
    #pragma unroll
    for (int j = 0; j < 4; ++j) {
        int row = bl0 + ty + j * 8;
        int col = t0 + tx;
        if (col < TT) out[OUT_ATT + (long)row * TT + col] = tile[tx][ty + j * 8];
    }
}

extern "C" void kernel_launch(void* const* d_in, const int* in_sizes, int n_in,
                              void* d_out, int out_size, void* d_ws, size_t ws_size,
                              hipStream_t stream)
{
    const float* enc_key   = (const float*)d_in[0];
    const float* enc_value = (const float*)d_in[1];
    const int*   labels    = (const int*)d_in[2];
    const int*   fsl       = (const int*)d_in[3];
    const float* gumbel_u  = (const float*)d_in[4];
    const float* W_emb     = (const float*)d_in[5];
    const float* b_emb     = (const float*)d_in[6];
    const float* W_fc      = (const float*)d_in[7];
    const float* b_fc      = (const float*)d_in[8];
    const float* W_mlp1    = (const float*)d_in[9];
    const float* b_mlp1    = (const float*)d_in[10];
    const float* W_mlp2    = (const float*)d_in[11];
    const float* b_mlp2    = (const float*)d_in[12];
    const float* Wih0 = (const float*)d_in[13];
    const float* Whh0 = (const float*)d_in[14];
    const float* bih0 = (const float*)d_in[15];
    const float* bhh0 = (const float*)d_in[16];
    const float* Wih1 = (const float*)d_in[17];
    const float* Whh1 = (const float*)d_in[18];
    const float* bih1 = (const float*)d_in[19];
    const float* bhh1 = (const float*)d_in[20];
    const float* Wih2 = (const float*)d_in[21];
    const float* Whh2 = (const float*)d_in[22];
    const float* bih2 = (const float*)d_in[23];
    const float* bhh2 = (const float*)d_in[24];
    float* ws  = (float*)d_ws;
    float* out = (float*)d_out;

    const bool full = ws_size >= (size_t)WS_FLOATS_FULL * 4;
    float* attdst = full ? (ws + OFF_ATT) : (out + OUT_ATT);
    const int attDirect = full ? 0 : 1;

    hipLaunchKernelGGL(k_pack_gates, dim3(6168), dim3(256), 0, stream,
                       Wih0, Whh0, Wih1, Whh1, Wih2, Whh2,
                       bih0, bhh0, bih1, bhh1, bih2, bhh2, ws);
    hipLaunchKernelGGL(k_pack_small, dim3(483), dim3(256), 0, stream,
                       W_fc, W_mlp1, W_mlp2, W_emb, ws);
    hipLaunchKernelGGL(k_init, dim3(512), dim3(256), 0, stream, W_emb, b_emb, ws);

    for (int t = 0; t < TT; ++t) {
        hipLaunchKernelGGL(k_pa,    dim3(768), dim3(256), 0, stream, ws, t);
        hipLaunchKernelGGL(k_pbc,   dim3(256), dim3(256), 0, stream, ws, t, 1);
        hipLaunchKernelGGL(k_pbc,   dim3(256), dim3(256), 0, stream, ws, t, 2);
        hipLaunchKernelGGL(k_query, dim3(64),  dim3(256), 0, stream, b_fc, ws, t);
        hipLaunchKernelGGL(k_energy,dim3(256), dim3(256), 0, stream, enc_key, fsl, ws);
        hipLaunchKernelGGL(k_ctx,   dim3(256), dim3(256), 0, stream, enc_value, ws, attdst, attDirect, t);
        hipLaunchKernelGGL(k_final, dim3(64),  dim3(256), 0, stream, gumbel_u, b_mlp1, b_mlp2, b_emb, ws, out, t);
    }
    hipLaunchKernelGGL(k_labels, dim3(75), dim3(256), 0, stream, labels, out);
    if (full) hipLaunchKernelGGL(k_att_tr, dim3(2048, 10), dim3(256), 0, stream, ws + OFF_ATT, out);
}